// Round 9
// baseline (18.436 us; speedup 1.0000x reference)
//
#include <hip/hip_runtime.h>

// HiddenMerger: the masked softmax's diagonal is exactly 0 for rows m>=1
// (diagonal masked with -2^32; exp underflows in fp32) and exactly 1/L for
// row 0 (every entry of row 0 rounds to exactly -2^32 -> uniform softmax).
//   out[b,0,d]    = (1/L) * sum_l hidden[b,l,d]
//   out[b,m>=1,d] = 0
// Best measured structure (R6, 14.73 us): single dispatch, 256 blocks x 512
// threads (8 waves/CU), roles interleaved by bid&1:
//   even bid (128 blocks): sum block owns an 8-float4 (128 B = full cache
//     line) column slice of one batch; sums it over all L rows (64 row-ways
//     x unroll 16), LDS-reduces, writes its 128 B of row 0 scaled by 1/L.
//   odd bid (128 blocks): zero block, grid-strides over 4096 adjacent
//     row-pairs, 8 KB contiguous zeros per iteration (row 0 skipped).
// This round's delta: nontemporal load/store hints (touch-once streams,
// skip L2 allocation). Traffic: 33.5 MB read + 33.5 MB write, each line
// touched exactly once. Fixed reduction order -> bit-deterministic.

typedef float f32x4 __attribute__((ext_vector_type(4)));

namespace {
constexpr int B = 4;
constexpr int L = 2048;
constexpr int D = 1024;
constexpr int D4 = D / 4;           // 256 f32x4 per row
constexpr int NT = 512;             // threads per block
constexpr int CI = 8;               // f32x4 columns per sum slice (128 B)
constexpr int CHUNKS = D4 / CI;     // 32 column slices per batch
constexpr int WAYS = NT / CI;       // 64 row-ways per sum block
constexpr int NSUM = CHUNKS * B;    // 128 sum blocks
constexpr int NZB = 128;            // zero blocks
constexpr int NPAIR = B * L / 2;    // 4096 flat row-pairs
}

__global__ __launch_bounds__(NT) void k_fused(const float* __restrict__ hidden,
                                              float* __restrict__ out) {
    const int bid = blockIdx.x;
    const int t = threadIdx.x;

    if ((bid & 1) == 0) {
        // ---- sum role ----
        const int sidx = bid >> 1;          // 0..127
        const int c = sidx & (CHUNKS - 1);  // column slice 0..31
        const int b = sidx >> 5;            // batch 0..3
        const int ci = t & (CI - 1);        // f32x4 column within slice
        const int ri = t >> 3;              // row-way 0..63
        const int colf4 = c * CI + ci;      // 0..255

        const f32x4* hp = reinterpret_cast<const f32x4*>(hidden + (size_t)b * L * D);
        f32x4 s = {0.f, 0.f, 0.f, 0.f};
#pragma unroll 16
        for (int r = ri; r < L; r += WAYS)              // 32 iterations
            s += __builtin_nontemporal_load(&hp[(size_t)r * D4 + colf4]);

        __shared__ f32x4 red[NT];
        red[t] = s;
        __syncthreads();
#pragma unroll
        for (int sh = WAYS / 2; sh > 0; sh >>= 1) {     // 64 -> 1, fixed order
            if (ri < sh)
                red[t] += red[(ri + sh) * CI + ci];
            __syncthreads();
        }
        if (ri == 0) {
            f32x4 m = red[ci] * (1.0f / (float)L);      // 2^-11, exact
            __builtin_nontemporal_store(
                m, &reinterpret_cast<f32x4*>(out + (size_t)b * L * D)[colf4]);
        }
    } else {
        // ---- zero role: grid-stride over adjacent flat row-pairs ----
        const int zidx = bid >> 1;          // 0..127
        const int rp = t >> 8;              // 0..1: which row of the pair
        const int col = t & (D4 - 1);       // f4 column 0..255
        const f32x4 zero = {0.f, 0.f, 0.f, 0.f};
        for (int p = zidx; p < NPAIR; p += NZB) {       // 32 iterations
            const int fr = 2 * p + rp;      // flat row 0..8191
            const int row = fr & (L - 1);
            if (row > 0)                    // batch row 0 gets the sum instead
                __builtin_nontemporal_store(
                    zero, &reinterpret_cast<f32x4*>(out)[(size_t)fr * D4 + col]);
        }
    }
}

extern "C" void kernel_launch(void* const* d_in, const int* in_sizes, int n_in,
                              void* d_out, int out_size, void* d_ws, size_t ws_size,
                              hipStream_t stream) {
    const float* hidden = (const float*)d_in[0];
    float* out = (float*)d_out;
    hipLaunchKernelGGL(k_fused, dim3(NSUM + NZB), dim3(NT), 0, stream, hidden, out);
}

// Round 10
// 14.575 us; speedup vs baseline: 1.2649x; 1.2649x over previous
//
#include <hip/hip_runtime.h>

// HiddenMerger: the masked softmax's diagonal is exactly 0 for rows m>=1
// (diagonal masked with -2^32; exp underflows in fp32) and exactly 1/L for
// row 0 (every entry of row 0 rounds to exactly -2^32 -> uniform softmax).
//   out[b,0,d]    = (1/L) * sum_l hidden[b,l,d]
//   out[b,m>=1,d] = 0
// FINAL (revert to R6, best measured 14.73 us; R9's nontemporal hints hurt
// because the input stays L3-resident across graph replays — nt bypasses L3).
// Single dispatch, 256 blocks x 512 threads (8 waves/CU), roles interleaved
// by bid&1 so every XCD carries a balanced read/write mix:
//   even bid (128 blocks): sum block owns an 8-float4 (128 B = full cache
//     line) column slice of one batch; sums it over all L rows with 64
//     row-ways x unroll 16, LDS-reduces, writes its 128 B of row 0 x (1/L).
//   odd bid (128 blocks): zero block, grid-strides over 4096 adjacent
//     row-pairs, storing 8 KB contiguous zeros per iteration (row 0 skipped).
// Traffic: 33.5 MB read + 33.5 MB write, every line touched exactly once.
// Fixed reduction order -> bit-deterministic (absmax 0.0 vs numpy ref).

namespace {
constexpr int B = 4;
constexpr int L = 2048;
constexpr int D = 1024;
constexpr int D4 = D / 4;           // 256 float4 per row
constexpr int NT = 512;             // threads per block
constexpr int CI = 8;               // float4 columns per sum slice (128 B)
constexpr int CHUNKS = D4 / CI;     // 32 column slices per batch
constexpr int WAYS = NT / CI;       // 64 row-ways per sum block
constexpr int NSUM = CHUNKS * B;    // 128 sum blocks
constexpr int NZB = 128;            // zero blocks
constexpr int NPAIR = B * L / 2;    // 4096 flat row-pairs
}

__global__ __launch_bounds__(NT) void k_fused(const float* __restrict__ hidden,
                                              float* __restrict__ out) {
    const int bid = blockIdx.x;
    const int t = threadIdx.x;

    if ((bid & 1) == 0) {
        // ---- sum role ----
        const int sidx = bid >> 1;          // 0..127
        const int c = sidx & (CHUNKS - 1);  // column slice 0..31
        const int b = sidx >> 5;            // batch 0..3
        const int ci = t & (CI - 1);        // float4 column within slice
        const int ri = t >> 3;              // row-way 0..63
        const int colf4 = c * CI + ci;      // 0..255

        const float4* hp = reinterpret_cast<const float4*>(hidden + (size_t)b * L * D);
        float4 s = make_float4(0.f, 0.f, 0.f, 0.f);
#pragma unroll 16
        for (int r = ri; r < L; r += WAYS) {            // 32 iterations
            float4 v = hp[(size_t)r * D4 + colf4];
            s.x += v.x; s.y += v.y; s.z += v.z; s.w += v.w;
        }

        __shared__ float4 red[NT];
        red[t] = s;
        __syncthreads();
#pragma unroll
        for (int sh = WAYS / 2; sh > 0; sh >>= 1) {     // 64 -> 1, fixed order
            if (ri < sh) {
                float4 o = red[(ri + sh) * CI + ci];
                float4 m = red[t];
                m.x += o.x; m.y += o.y; m.z += o.z; m.w += o.w;
                red[t] = m;
            }
            __syncthreads();
        }
        if (ri == 0) {
            float4 m = red[ci];
            const float sc = 1.0f / (float)L;           // 2^-11, exact
            m.x *= sc; m.y *= sc; m.z *= sc; m.w *= sc;
            reinterpret_cast<float4*>(out + (size_t)b * L * D)[colf4] = m;
        }
    } else {
        // ---- zero role: grid-stride over adjacent flat row-pairs ----
        const int zidx = bid >> 1;          // 0..127
        const int rp = t >> 8;              // 0..1: which row of the pair
        const int col = t & (D4 - 1);       // f4 column 0..255
        const float4 zero = make_float4(0.f, 0.f, 0.f, 0.f);
        for (int p = zidx; p < NPAIR; p += NZB) {       // 32 iterations
            const int fr = 2 * p + rp;      // flat row 0..8191
            const int row = fr & (L - 1);
            if (row > 0)                    // batch row 0 gets the sum instead
                reinterpret_cast<float4*>(out)[(size_t)fr * D4 + col] = zero;
        }
    }
}

extern "C" void kernel_launch(void* const* d_in, const int* in_sizes, int n_in,
                              void* d_out, int out_size, void* d_ws, size_t ws_size,
                              hipStream_t stream) {
    const float* hidden = (const float*)d_in[0];
    float* out = (float*)d_out;
    hipLaunchKernelGGL(k_fused, dim3(NSUM + NZB), dim3(NT), 0, stream, hidden, out);
}